// Round 9
// baseline (386.893 us; speedup 1.0000x reference)
//
#include <hip/hip_runtime.h>

#define DD 64
#define NBUCK 256
#define BSTRIDE 32   // doubles; 256B spacing -> distinct L2 lines
#define CAP 13312    // slots per coarse bucket (max observed ~8600, 1.5x margin)
#define GSTRIDE 16   // ints; 64B spacing for global cursors
#define TILE 4096    // edges per bucket_a block
#define BSLACK 8192  // per-bucket csr padding slack (512 nodes * 16 max pad incl self)

__device__ __forceinline__ unsigned pack_bf16_2(float a, float b) {
  unsigned ua = __float_as_uint(a);
  unsigned ub = __float_as_uint(b);
  unsigned ra = (ua + 0x7FFFu + ((ua >> 16) & 1u)) >> 16;
  unsigned rb = (ub + 0x7FFFu + ((ub >> 16) & 1u)) >> 16;
  return ra | (rb << 16);
}

__device__ __forceinline__ float4 unpack_bf16_4(uint2 p) {
  float4 f;
  f.x = __uint_as_float(p.x << 16);
  f.y = __uint_as_float(p.x & 0xFFFF0000u);
  f.z = __uint_as_float(p.y << 16);
  f.w = __uint_as_float(p.y & 0xFFFF0000u);
  return f;
}

// block-wide LN stats from the 256 reduction buckets (blockDim must be 256)
__device__ __forceinline__ void ln_stats(const double* __restrict__ buckets, int M,
                                         float* mean_out, float* rstd_out) {
  __shared__ double ra[4], rb[4];
  __shared__ float sm[2];
  int t = threadIdx.x;
  double a = buckets[(size_t)t * BSTRIDE];
  double b = buckets[(size_t)t * BSTRIDE + 1];
#pragma unroll
  for (int o = 1; o <= 32; o <<= 1) {
    a += __shfl_xor(a, o);
    b += __shfl_xor(b, o);
  }
  if ((t & 63) == 0) { ra[t >> 6] = a; rb[t >> 6] = b; }
  __syncthreads();
  if (t == 0) {
    double s1 = ra[0] + ra[1] + ra[2] + ra[3];
    double s2 = rb[0] + rb[1] + rb[2] + rb[3];
    double mean = s1 / M;
    double var = s2 / M - mean * mean;
    sm[0] = (float)mean;
    sm[1] = (float)rsqrt(var + 1e-5);
  }
  __syncthreads();
  *mean_out = sm[0];
  *rstd_out = sm[1];
}

// ---------------- CSR build: two-pass bucket sort ----------------

__global__ __launch_bounds__(256) void init_gcur_k(int* __restrict__ gcur, int nbkt) {
  int t = blockIdx.x * 256 + threadIdx.x;
  if (t < nbkt) gcur[t * GSTRIDE] = t * CAP;
}

// Pass A: group edges by coarse bucket (dst>>9). Packed entry = src | (dst&511)<<17.
__global__ __launch_bounds__(256) void bucket_a_k(const int* __restrict__ src, const int* __restrict__ dst,
                                                  int* __restrict__ gcur, unsigned* __restrict__ slots, int E) {
  __shared__ int hist[256], cur[256], hbase[256];
  int t = threadIdx.x;
  hist[t] = 0;
  cur[t] = 0;
  __syncthreads();
  int t0 = blockIdx.x * TILE;
  unsigned pk[16];
  int bk[16];
#pragma unroll
  for (int k = 0; k < 16; ++k) {
    int e = t0 + k * 256 + t;
    if (e < E) {
      int s = src[e], d = dst[e];
      bk[k] = d >> 9;
      pk[k] = (unsigned)s | ((unsigned)(d & 511) << 17);
      atomicAdd(&hist[bk[k]], 1);
    } else {
      bk[k] = -1;
      pk[k] = 0;
    }
  }
  __syncthreads();
  if (hist[t] > 0) hbase[t] = atomicAdd(&gcur[t * GSTRIDE], hist[t]);
  __syncthreads();
#pragma unroll
  for (int k = 0; k < 16; ++k) {
    if (bk[k] >= 0) {
      int r = atomicAdd(&cur[bk[k]], 1);
      slots[(size_t)hbase[bk[k]] + r] = pk[k];
    }
  }
}

// exclusive scan of per-bucket raw counts -> CSR bucket bases (1 block, 256 thr)
__global__ __launch_bounds__(256) void scan_nb_k(const int* __restrict__ gcur, int* __restrict__ bbase, int nbkt) {
  __shared__ int ts[256];
  int t = threadIdx.x;
  int c = (t < nbkt) ? (gcur[t * GSTRIDE] - t * CAP) : 0;
  ts[t] = c;
  __syncthreads();
  for (int o = 1; o < 256; o <<= 1) {
    int u = (t >= o) ? ts[t - o] : 0;
    __syncthreads();
    ts[t] += u;
    __syncthreads();
  }
  if (t < nbkt) bbase[t] = ts[t] - c;
}

// Pass B: per-bucket counting sort by local dst; writes off2 (start, padded_end),
// dinv, csr (src-only 4B). Node's own index is INSERTED into its segment (self
// term is algebraically inside the dd* sum); segment padded to x16 with
// sentinel N (hwb row N is zero) so agg needs no bounds predicates.
__global__ __launch_bounds__(256) void bucket_b_k(const unsigned* __restrict__ slots,
                                                  const int* __restrict__ gcur, const int* __restrict__ bbase,
                                                  int2* __restrict__ off2, float* __restrict__ dinv,
                                                  int* __restrict__ csr, int N) {
  __shared__ int hist[512], excl[512], ts[256];
  int b = blockIdx.x, t = threadIdx.x;
  int base = b * CAP;
  int cnt = gcur[b * GSTRIDE] - base;
  if (cnt > CAP) cnt = CAP;
  int cbase = bbase[b] + b * BSLACK;  // padded bucket base
  int node0 = b << 9;
  hist[t] = 0;
  hist[t + 256] = 0;
  __syncthreads();
  for (int i = t; i < cnt; i += 256) atomicAdd(&hist[slots[(size_t)base + i] >> 17], 1);
  __syncthreads();
  int h0 = hist[2 * t], h1 = hist[2 * t + 1];
  int p0 = (h0 + 16) & ~15, p1 = (h1 + 16) & ~15;  // always >= h+1 (room for self)
  int pair = p0 + p1;
  ts[t] = pair;
  __syncthreads();
  for (int o = 1; o < 256; o <<= 1) {
    int u = (t >= o) ? ts[t - o] : 0;
    __syncthreads();
    ts[t] += u;
    __syncthreads();
  }
  int ep = ts[t] - pair;
  int start0 = cbase + ep, start1 = cbase + ep + p0;
  int j0 = node0 + 2 * t, j1 = j0 + 1;
  if (j0 < N) { off2[j0] = make_int2(start0, start0 + p0); dinv[j0] = rsqrtf((float)h0 + 1.0f); }
  if (j1 < N) { off2[j1] = make_int2(start1, start1 + p1); dinv[j1] = rsqrtf((float)h1 + 1.0f); }
  excl[2 * t] = start0;
  excl[2 * t + 1] = start1;
  __syncthreads();
  for (int i = t; i < cnt; i += 256) {
    unsigned e = slots[(size_t)base + i];
    int pos = atomicAdd(&excl[e >> 17], 1);
    csr[pos] = (int)(e & 0x1FFFFu);
  }
  __syncthreads();
  // insert self, then sentinel-fill the padding of this thread's two nodes
  csr[start0 + h0] = (j0 < N) ? j0 : N;
  for (int i = h0 + 1; i < p0; ++i) csr[start0 + i] = N;
  csr[start1 + h1] = (j1 < N) ? j1 : N;
  for (int i = h1 + 1; i < p1; ++i) csr[start1 + i] = N;
}

// ---------------- per-layer kernels ----------------

// hwb[row] = bf16( dinv[row] * (act(in[row]) @ W) ); act = id (l=0) or relu(ln(.))
// LN stats are reduced in-block from the previous layer's buckets (finalize fused).
__global__ __launch_bounds__(256) void gemm_ln_k(const float* __restrict__ in, const float* __restrict__ W,
                                                 uint4* __restrict__ hwb, const float* __restrict__ dinv,
                                                 const float* __restrict__ lnw, const float* __restrict__ lnb,
                                                 const double* __restrict__ buckets, int M,
                                                 int applyLn, int n) {
  __shared__ float Wl[64 * 64];
  __shared__ float Al[64 * 68];
  int t = threadIdx.x;
  float mean = 0.f, rstd = 1.f;
  if (applyLn) ln_stats(buckets, M, &mean, &rstd);
#pragma unroll
  for (int i = 0; i < 4; ++i)
    ((float4*)Wl)[t + i * 256] = ((const float4*)W)[t + i * 256];
  int row0 = blockIdx.x * 64;
#pragma unroll
  for (int i = 0; i < 4; ++i) {
    int q = t + i * 256;
    int r = q >> 4, c4 = q & 15;
    int gr = row0 + r;
    float4 v = make_float4(0.f, 0.f, 0.f, 0.f);
    if (gr < n) v = ((const float4*)in)[(size_t)gr * 16 + c4];
    if (applyLn) {
      int c = c4 * 4;
      v.x = fmaxf(fmaf((v.x - mean) * rstd, lnw[c + 0], lnb[c + 0]), 0.f);
      v.y = fmaxf(fmaf((v.y - mean) * rstd, lnw[c + 1], lnb[c + 1]), 0.f);
      v.z = fmaxf(fmaf((v.z - mean) * rstd, lnw[c + 2], lnb[c + 2]), 0.f);
      v.w = fmaxf(fmaf((v.w - mean) * rstd, lnw[c + 3], lnb[c + 3]), 0.f);
    }
    *(float4*)&Al[r * 68 + c4 * 4] = v;
  }
  __syncthreads();
  int r = t >> 2, cb = (t & 3) * 16;
  float acc[16];
#pragma unroll
  for (int j = 0; j < 16; ++j) acc[j] = 0.f;
  for (int k = 0; k < 64; ++k) {
    float a = Al[r * 68 + k];
#pragma unroll
    for (int j = 0; j < 16; ++j) acc[j] = fmaf(a, Wl[k * 64 + cb + j], acc[j]);
  }
  int gr = row0 + r;
  if (gr < n) {
    float di = dinv[gr];
#pragma unroll
    for (int j = 0; j < 16; ++j) acc[j] *= di;
    uint4 u0, u1;
    u0.x = pack_bf16_2(acc[0], acc[1]);
    u0.y = pack_bf16_2(acc[2], acc[3]);
    u0.z = pack_bf16_2(acc[4], acc[5]);
    u0.w = pack_bf16_2(acc[6], acc[7]);
    u1.x = pack_bf16_2(acc[8], acc[9]);
    u1.y = pack_bf16_2(acc[10], acc[11]);
    u1.z = pack_bf16_2(acc[12], acc[13]);
    u1.w = pack_bf16_2(acc[14], acc[15]);
    hwb[(size_t)gr * 8 + (t & 3) * 2 + 0] = u0;
    hwb[(size_t)gr * 8 + (t & 3) * 2 + 1] = u1;
  }
}

// 8 nodes per wave processed as 4 ping-pong PAIRS: both nodes' csr loads then
// all 8 row-gathers issued before any consumption (2x memory-level parallelism
// on the latency-dominated path). Self term is inside the csr list; sentinel
// rows read zeros. One LN reduce+atomic per block.
__global__ __launch_bounds__(256) void agg_k(const uint2* __restrict__ hwb, const int2* __restrict__ off2,
                                             const int* __restrict__ csr, const float* __restrict__ dinv,
                                             const float4* __restrict__ bias4, float4* __restrict__ out4,
                                             double* __restrict__ buckets, int n) {
  int t = threadIdx.x;
  int lane = t & 63;
  int w = t >> 6;
  int g = lane >> 4, q = lane & 15;
  int wbase = (blockIdx.x * 4 + w) * 8;
  float s1 = 0.f, s2 = 0.f;
  float4 bq = bias4[q];
#pragma unroll 1
  for (int pr = 0; pr < 4; ++pr) {
    int wid0 = wbase + 2 * pr;
    int wid1 = wid0 + 1;
    if (wid0 >= n) break;
    int4 oo;
    if (wid1 < n) {
      oo = *(const int4*)(off2 + wid0);  // both nodes' (start,end) in one load
    } else {
      int2 o0 = off2[wid0];
      oo = make_int4(o0.x, o0.y, 0, 0);
    }
    float4 a0 = make_float4(0.f, 0.f, 0.f, 0.f);
    float4 a1 = make_float4(0.f, 0.f, 0.f, 0.f);
    int b0 = oo.x, e0 = oo.y, b1 = oo.z, e1 = oo.w;
    while (b0 < e0 || b1 < e1) {
      bool d0 = b0 < e0, d1 = b1 < e1;
      int4 c0 = d0 ? *(const int4*)(csr + b0 + g * 4) : make_int4(n, n, n, n);
      int4 c1 = d1 ? *(const int4*)(csr + b1 + g * 4) : make_int4(n, n, n, n);
      float4 u00 = unpack_bf16_4(hwb[(size_t)c0.x * 16 + q]);
      float4 u01 = unpack_bf16_4(hwb[(size_t)c0.y * 16 + q]);
      float4 u02 = unpack_bf16_4(hwb[(size_t)c0.z * 16 + q]);
      float4 u03 = unpack_bf16_4(hwb[(size_t)c0.w * 16 + q]);
      float4 u10 = unpack_bf16_4(hwb[(size_t)c1.x * 16 + q]);
      float4 u11 = unpack_bf16_4(hwb[(size_t)c1.y * 16 + q]);
      float4 u12 = unpack_bf16_4(hwb[(size_t)c1.z * 16 + q]);
      float4 u13 = unpack_bf16_4(hwb[(size_t)c1.w * 16 + q]);
      a0.x += (u00.x + u01.x) + (u02.x + u03.x);
      a0.y += (u00.y + u01.y) + (u02.y + u03.y);
      a0.z += (u00.z + u01.z) + (u02.z + u03.z);
      a0.w += (u00.w + u01.w) + (u02.w + u03.w);
      a1.x += (u10.x + u11.x) + (u12.x + u13.x);
      a1.y += (u10.y + u11.y) + (u12.y + u13.y);
      a1.z += (u10.z + u11.z) + (u12.z + u13.z);
      a1.w += (u10.w + u11.w) + (u12.w + u13.w);
      if (d0) b0 += 16;
      if (d1) b1 += 16;
    }
    // combine quarter-wave partials (lanes q, q+16, q+32, q+48) for both nodes
#pragma unroll
    for (int o = 16; o <= 32; o <<= 1) {
      a0.x += __shfl_xor(a0.x, o);
      a0.y += __shfl_xor(a0.y, o);
      a0.z += __shfl_xor(a0.z, o);
      a0.w += __shfl_xor(a0.w, o);
      a1.x += __shfl_xor(a1.x, o);
      a1.y += __shfl_xor(a1.y, o);
      a1.z += __shfl_xor(a1.z, o);
      a1.w += __shfl_xor(a1.w, o);
    }
    if (g == 0) {
      float dd0 = dinv[wid0];
      a0.x = fmaf(dd0, a0.x, bq.x);
      a0.y = fmaf(dd0, a0.y, bq.y);
      a0.z = fmaf(dd0, a0.z, bq.z);
      a0.w = fmaf(dd0, a0.w, bq.w);
      out4[(size_t)wid0 * 16 + q] = a0;
      s1 += a0.x + a0.y + a0.z + a0.w;
      s2 += a0.x * a0.x + a0.y * a0.y + a0.z * a0.z + a0.w * a0.w;
      if (wid1 < n) {
        float dd1 = dinv[wid1];
        a1.x = fmaf(dd1, a1.x, bq.x);
        a1.y = fmaf(dd1, a1.y, bq.y);
        a1.z = fmaf(dd1, a1.z, bq.z);
        a1.w = fmaf(dd1, a1.w, bq.w);
        out4[(size_t)wid1 * 16 + q] = a1;
        s1 += a1.x + a1.y + a1.z + a1.w;
        s2 += a1.x * a1.x + a1.y * a1.y + a1.z * a1.z + a1.w * a1.w;
      }
    }
  }
  // one full-wave reduce per wave (only g==0 lanes hold nonzero partials)
#pragma unroll
  for (int o = 1; o <= 32; o <<= 1) {
    s1 += __shfl_xor(s1, o);
    s2 += __shfl_xor(s2, o);
  }
  __shared__ float red1[4], red2[4];
  if (lane == 0) { red1[w] = s1; red2[w] = s2; }
  __syncthreads();
  if (t == 0) {
    double a = (double)red1[0] + (double)red1[1] + (double)red1[2] + (double)red1[3];
    double b = (double)red2[0] + (double)red2[1] + (double)red2[2] + (double)red2[3];
    double* bp = buckets + (size_t)(blockIdx.x & (NBUCK - 1)) * BSTRIDE;
    atomicAdd(&bp[0], a);
    atomicAdd(&bp[1], b);
  }
}

// final layer: in-place ln+relu on d_out (stats reduced in-block; grid-stride)
__global__ __launch_bounds__(256) void norm_relu_k(float4* __restrict__ io, const float* __restrict__ lnw,
                                                   const float* __restrict__ lnb,
                                                   const double* __restrict__ buckets, int M, int n4) {
  float mean, rstd;
  ln_stats(buckets, M, &mean, &rstd);
  for (int i = blockIdx.x * 256 + threadIdx.x; i < n4; i += gridDim.x * 256) {
    float4 v = io[i];
    int c = (i & 15) * 4;
    v.x = fmaxf(fmaf((v.x - mean) * rstd, lnw[c + 0], lnb[c + 0]), 0.f);
    v.y = fmaxf(fmaf((v.y - mean) * rstd, lnw[c + 1], lnb[c + 1]), 0.f);
    v.z = fmaxf(fmaf((v.z - mean) * rstd, lnw[c + 2], lnb[c + 2]), 0.f);
    v.w = fmaxf(fmaf((v.w - mean) * rstd, lnw[c + 3], lnb[c + 3]), 0.f);
    io[i] = v;
  }
}

// ---------------- launch ----------------

extern "C" void kernel_launch(void* const* d_in, const int* in_sizes, int n_in,
                              void* d_out, int out_size, void* d_ws, size_t ws_size,
                              hipStream_t stream) {
  const float* x = (const float*)d_in[0];
  const int* ei = (const int*)d_in[1];
  const float* Ws = (const float*)d_in[2];
  const float* bs = (const float*)d_in[3];
  const float* lnw = (const float*)d_in[4];
  const float* lnb = (const float*)d_in[5];
  float* out = (float*)d_out;

  const int N = in_sizes[0] / DD;
  const int E = in_sizes[1] / 2;
  const int L = in_sizes[2] / (DD * DD);
  const int* srcp = ei;
  const int* dstp = ei + E;
  const int nbkt = (N + 511) >> 9;  // <= 256 for N <= 131072

  char* p = (char*)d_ws;
  size_t ofs = 0;
  auto carve = [&](size_t bytes) -> void* {
    void* r = p + ofs;
    ofs = (ofs + bytes + 255) & ~(size_t)255;
    return r;
  };
  int* gcur = (int*)carve((size_t)256 * GSTRIDE * 4);
  int* bbase = (int*)carve((size_t)256 * 4);
  unsigned* slots = (unsigned*)carve((size_t)256 * CAP * 4);
  double* buckets = (double*)carve((size_t)NBUCK * BSTRIDE * 8 * 4);  // per-layer sets
  int2* off2 = (int2*)carve((size_t)N * 8);
  float* dinv = (float*)carve((size_t)N * 4);
  int* csr = (int*)carve(((size_t)E + (size_t)nbkt * BSLACK + 64) * 4);
  uint4* hwb = (uint4*)carve((size_t)(N + 1) * DD * 2);  // bf16 dinv*(h@W), +1 zero row

  hipMemsetAsync(buckets, 0, (size_t)NBUCK * BSTRIDE * 8 * 4, stream);
  hipMemsetAsync(hwb + (size_t)N * 8, 0, DD * 2, stream);  // sentinel row N = 0

  init_gcur_k<<<1, 256, 0, stream>>>(gcur, nbkt);
  int nTiles = (E + TILE - 1) / TILE;
  bucket_a_k<<<nTiles, 256, 0, stream>>>(srcp, dstp, gcur, slots, E);
  scan_nb_k<<<1, 256, 0, stream>>>(gcur, bbase, nbkt);
  bucket_b_k<<<nbkt, 256, 0, stream>>>(slots, gcur, bbase, off2, dinv, csr, N);

  int gGemm = (N + 63) / 64;
  int gAgg = (N + 31) / 32;  // 4 waves/block, 8 nodes/wave
  for (int l = 0; l < L; ++l) {
    const float* in = (l == 0) ? x : out;
    const float* plnw = (l == 0) ? lnw : lnw + (l - 1) * DD;
    const float* plnb = (l == 0) ? lnb : lnb + (l - 1) * DD;
    const double* pbuck = buckets + (size_t)((l == 0) ? 0 : (l - 1)) * NBUCK * BSTRIDE;
    gemm_ln_k<<<gGemm, 256, 0, stream>>>(in, Ws + (size_t)l * DD * DD, hwb, dinv, plnw, plnb,
                                         pbuck, N * DD, (l > 0) ? 1 : 0, N);
    double* lbuck = buckets + (size_t)l * NBUCK * BSTRIDE;
    agg_k<<<gAgg, 256, 0, stream>>>((const uint2*)hwb, off2, csr, dinv,
                                    (const float4*)(bs + (size_t)l * DD), (float4*)out,
                                    lbuck, N);
  }
  norm_relu_k<<<1024, 256, 0, stream>>>((float4*)out, lnw + (size_t)(L - 1) * DD,
                                        lnb + (size_t)(L - 1) * DD,
                                        buckets + (size_t)(L - 1) * NBUCK * BSTRIDE,
                                        N * DD, N * (DD / 4));
}

// Round 10
// 311.772 us; speedup vs baseline: 1.2410x; 1.2410x over previous
//
#include <hip/hip_runtime.h>

#define DD 64
#define NBUCK 256
#define BSTRIDE 32   // doubles; 256B spacing -> distinct L2 lines
#define CAP 13312    // slots per coarse bucket (max observed ~8600, 1.5x margin)
#define GSTRIDE 16   // ints; 64B spacing for global cursors
#define TILE 4096    // edges per bucket_a block
#define BSLACK 8192  // per-bucket csr padding slack (512 nodes * 15 max pad)

typedef __attribute__((ext_vector_type(8))) short bf16x8;
typedef __attribute__((ext_vector_type(4))) float f32x4;

__device__ __forceinline__ unsigned pack_bf16_2(float a, float b) {
  unsigned ua = __float_as_uint(a);
  unsigned ub = __float_as_uint(b);
  unsigned ra = (ua + 0x7FFFu + ((ua >> 16) & 1u)) >> 16;
  unsigned rb = (ub + 0x7FFFu + ((ub >> 16) & 1u)) >> 16;
  return ra | (rb << 16);
}

__device__ __forceinline__ unsigned short f2bf(float f) {
  unsigned u = __float_as_uint(f);
  return (unsigned short)((u + 0x7FFFu + ((u >> 16) & 1u)) >> 16);
}

__device__ __forceinline__ float4 unpack_bf16_4(uint2 p) {
  float4 f;
  f.x = __uint_as_float(p.x << 16);
  f.y = __uint_as_float(p.x & 0xFFFF0000u);
  f.z = __uint_as_float(p.y << 16);
  f.w = __uint_as_float(p.y & 0xFFFF0000u);
  return f;
}

// block-wide LN stats from the 256 reduction buckets (blockDim must be 256)
__device__ __forceinline__ void ln_stats(const double* __restrict__ buckets, int M,
                                         float* mean_out, float* rstd_out) {
  __shared__ double ra[4], rb[4];
  __shared__ float sm[2];
  int t = threadIdx.x;
  double a = buckets[(size_t)t * BSTRIDE];
  double b = buckets[(size_t)t * BSTRIDE + 1];
#pragma unroll
  for (int o = 1; o <= 32; o <<= 1) {
    a += __shfl_xor(a, o);
    b += __shfl_xor(b, o);
  }
  if ((t & 63) == 0) { ra[t >> 6] = a; rb[t >> 6] = b; }
  __syncthreads();
  if (t == 0) {
    double s1 = ra[0] + ra[1] + ra[2] + ra[3];
    double s2 = rb[0] + rb[1] + rb[2] + rb[3];
    double mean = s1 / M;
    double var = s2 / M - mean * mean;
    sm[0] = (float)mean;
    sm[1] = (float)rsqrt(var + 1e-5);
  }
  __syncthreads();
  *mean_out = sm[0];
  *rstd_out = sm[1];
}

// ---------------- CSR build: two-pass bucket sort ----------------

// Pass A: group edges by coarse bucket (dst>>9). Packed entry = src | (dst&511)<<17.
// gcur holds COUNTS (memset 0); slot base = t*CAP + old_count.
__global__ __launch_bounds__(256) void bucket_a_k(const int* __restrict__ src, const int* __restrict__ dst,
                                                  int* __restrict__ gcur, unsigned* __restrict__ slots, int E) {
  __shared__ int hist[256], cur[256], hbase[256];
  int t = threadIdx.x;
  hist[t] = 0;
  cur[t] = 0;
  __syncthreads();
  int t0 = blockIdx.x * TILE;
  unsigned pk[16];
  int bk[16];
#pragma unroll
  for (int k = 0; k < 16; ++k) {
    int e = t0 + k * 256 + t;
    if (e < E) {
      int s = src[e], d = dst[e];
      bk[k] = d >> 9;
      pk[k] = (unsigned)s | ((unsigned)(d & 511) << 17);
      atomicAdd(&hist[bk[k]], 1);
    } else {
      bk[k] = -1;
      pk[k] = 0;
    }
  }
  __syncthreads();
  if (hist[t] > 0) hbase[t] = t * CAP + atomicAdd(&gcur[t * GSTRIDE], hist[t]);
  __syncthreads();
#pragma unroll
  for (int k = 0; k < 16; ++k) {
    if (bk[k] >= 0) {
      int r = atomicAdd(&cur[bk[k]], 1);
      slots[(size_t)hbase[bk[k]] + r] = pk[k];
    }
  }
}

// exclusive scan of per-bucket raw counts -> CSR bucket bases (1 block, 256 thr)
__global__ __launch_bounds__(256) void scan_nb_k(const int* __restrict__ gcur, int* __restrict__ bbase, int nbkt) {
  __shared__ int ts[256];
  int t = threadIdx.x;
  int c = (t < nbkt) ? gcur[t * GSTRIDE] : 0;
  ts[t] = c;
  __syncthreads();
  for (int o = 1; o < 256; o <<= 1) {
    int u = (t >= o) ? ts[t - o] : 0;
    __syncthreads();
    ts[t] += u;
    __syncthreads();
  }
  if (t < nbkt) bbase[t] = ts[t] - c;
}

// Pass B: per-bucket counting sort by local dst; writes off2 (start, padded_end),
// dinv, csr (src-only 4B). Segment padded to x16 with sentinel N (hwb row N = 0).
__global__ __launch_bounds__(256) void bucket_b_k(const unsigned* __restrict__ slots,
                                                  const int* __restrict__ gcur, const int* __restrict__ bbase,
                                                  int2* __restrict__ off2, float* __restrict__ dinv,
                                                  int* __restrict__ csr, int N) {
  __shared__ int hist[512], excl[512], ts[256];
  int b = blockIdx.x, t = threadIdx.x;
  int base = b * CAP;
  int cnt = gcur[b * GSTRIDE];
  if (cnt > CAP) cnt = CAP;
  int cbase = bbase[b] + b * BSLACK;  // padded bucket base
  int node0 = b << 9;
  hist[t] = 0;
  hist[t + 256] = 0;
  __syncthreads();
  for (int i = t; i < cnt; i += 256) atomicAdd(&hist[slots[(size_t)base + i] >> 17], 1);
  __syncthreads();
  int h0 = hist[2 * t], h1 = hist[2 * t + 1];
  int p0 = (h0 + 15) & ~15, p1 = (h1 + 15) & ~15;
  int pair = p0 + p1;
  ts[t] = pair;
  __syncthreads();
  for (int o = 1; o < 256; o <<= 1) {
    int u = (t >= o) ? ts[t - o] : 0;
    __syncthreads();
    ts[t] += u;
    __syncthreads();
  }
  int ep = ts[t] - pair;
  int start0 = cbase + ep, start1 = cbase + ep + p0;
  int j0 = node0 + 2 * t, j1 = j0 + 1;
  if (j0 < N) { off2[j0] = make_int2(start0, start0 + p0); dinv[j0] = rsqrtf((float)h0 + 1.0f); }
  if (j1 < N) { off2[j1] = make_int2(start1, start1 + p1); dinv[j1] = rsqrtf((float)h1 + 1.0f); }
  excl[2 * t] = start0;
  excl[2 * t + 1] = start1;
  __syncthreads();
  for (int i = t; i < cnt; i += 256) {
    unsigned e = slots[(size_t)base + i];
    int pos = atomicAdd(&excl[e >> 17], 1);
    csr[pos] = (int)(e & 0x1FFFFu);
  }
  __syncthreads();
  // sentinel-fill the padding of this thread's two nodes
  for (int i = h0; i < p0; ++i) csr[start0 + i] = N;
  for (int i = h1; i < p1; ++i) csr[start1 + i] = N;
}

// ---------------- per-layer kernels ----------------

// MFMA gemm: hwb[row] = bf16( dinv[row] * (act(in[row]) @ W) )
// act = id (l=0) or relu(ln(.)); LN stats reduced in-block (finalize fused).
// 4 waves/block, 64 rows/block; wave w does rows [w*16, w*16+16) x all 64 cols
// via 2 k-steps x 4 col-tiles of v_mfma_f32_16x16x32_bf16.
__global__ __launch_bounds__(256) void gemm_mfma_k(const float* __restrict__ in, const float* __restrict__ W,
                                                   uint4* __restrict__ hwb, const float* __restrict__ dinv,
                                                   const float* __restrict__ lnw, const float* __restrict__ lnb,
                                                   const double* __restrict__ buckets, int M,
                                                   int applyLn, int n) {
  __shared__ unsigned short ctile[4][16][72];  // 72: pad breaks 4-row bank alias, keeps 16B align
  int t = threadIdx.x;
  int w = t >> 6, lane = t & 63;
  int lm = lane & 15, lk = lane >> 4;  // fragment row/col = lm, k-group = lk
  float mean = 0.f, rstd = 1.f;
  if (applyLn) ln_stats(buckets, M, &mean, &rstd);

  // B fragments: bfrag[ks][ct][j] = W[ks*32 + lk*8 + j][ct*16 + lm]
  bf16x8 bfrag[2][4];
#pragma unroll
  for (int ks = 0; ks < 2; ++ks)
#pragma unroll
    for (int ct = 0; ct < 4; ++ct) {
      bf16x8 bb;
      int col = ct * 16 + lm;
      int kb = ks * 32 + lk * 8;
#pragma unroll
      for (int j = 0; j < 8; ++j) bb[j] = (short)f2bf(W[(kb + j) * 64 + col]);
      bfrag[ks][ct] = bb;
    }

  int row = blockIdx.x * 64 + w * 16 + lm;
  bool valid = row < n;
  // A fragments: afrag[ks][j] = act(in[row][ks*32 + lk*8 + j])
  bf16x8 afrag[2];
#pragma unroll
  for (int ks = 0; ks < 2; ++ks) {
    float4 v0 = make_float4(0.f, 0.f, 0.f, 0.f), v1 = v0;
    if (valid) {
      const float4* ip = (const float4*)in + (size_t)row * 16 + ks * 8 + lk * 2;
      v0 = ip[0];
      v1 = ip[1];
    }
    float vals[8] = {v0.x, v0.y, v0.z, v0.w, v1.x, v1.y, v1.z, v1.w};
    if (applyLn) {
      int cb = ks * 32 + lk * 8;
#pragma unroll
      for (int j = 0; j < 8; ++j)
        vals[j] = fmaxf(fmaf((vals[j] - mean) * rstd, lnw[cb + j], lnb[cb + j]), 0.f);
    }
    bf16x8 aa;
#pragma unroll
    for (int j = 0; j < 8; ++j) aa[j] = (short)f2bf(vals[j]);
    afrag[ks] = aa;
  }

  f32x4 acc[4];
#pragma unroll
  for (int ct = 0; ct < 4; ++ct) acc[ct] = (f32x4){0.f, 0.f, 0.f, 0.f};
#pragma unroll
  for (int ks = 0; ks < 2; ++ks)
#pragma unroll
    for (int ct = 0; ct < 4; ++ct)
      acc[ct] = __builtin_amdgcn_mfma_f32_16x16x32_bf16(afrag[ks], bfrag[ks][ct], acc[ct], 0, 0, 0);

  // epilogue: C[crow][ccol]: ccol = ct*16+lm, crow = lk*4 + r ; scale by dinv, pack bf16
#pragma unroll
  for (int r = 0; r < 4; ++r) {
    int grow = blockIdx.x * 64 + w * 16 + lk * 4 + r;
    float di = (grow < n) ? dinv[grow] : 0.f;
#pragma unroll
    for (int ct = 0; ct < 4; ++ct)
      ctile[w][lk * 4 + r][ct * 16 + lm] = f2bf(acc[ct][r] * di);
  }
  __syncthreads();
  // coalesced store: lane handles row lane>>2, quarter lane&3 (16 bf16 = 2 uint4)
  int srow = lane >> 2, sq = lane & 3;
  int grow = blockIdx.x * 64 + w * 16 + srow;
  if (grow < n) {
    const uint4* lp = (const uint4*)&ctile[w][srow][sq * 16];
    hwb[(size_t)grow * 8 + sq * 2 + 0] = lp[0];
    hwb[(size_t)grow * 8 + sq * 2 + 1] = lp[1];
  }
}

// 8 nodes per wave; quarter-wave (16 lanes) per edge, 4 bf16 (uint2) per lane.
// Sentinel-padded CSR: no predicates in the edge loop; int4 broadcast csr loads.
// LN s1/s2 kept in registers across the wave's nodes; one reduce+atomic per block.
__global__ __launch_bounds__(256) void agg_k(const uint2* __restrict__ hwb, const int2* __restrict__ off2,
                                             const int* __restrict__ csr, const float* __restrict__ dinv,
                                             const float4* __restrict__ bias4, float4* __restrict__ out4,
                                             double* __restrict__ buckets, int n) {
  int t = threadIdx.x;
  int lane = t & 63;
  int w = t >> 6;
  int g = lane >> 4, q = lane & 15;
  int wbase = (blockIdx.x * 4 + w) * 8;
  float s1 = 0.f, s2 = 0.f;
#pragma unroll 1
  for (int ni = 0; ni < 8; ++ni) {
    int wid = wbase + ni;
    if (wid >= n) break;
    int2 oo = off2[wid];
    float4 acc = make_float4(0.f, 0.f, 0.f, 0.f);
    if (g == 0) acc = unpack_bf16_4(hwb[(size_t)wid * 16 + q]);  // self term
    for (int base = oo.x; base < oo.y; base += 16) {
      int4 c = *(const int4*)(csr + base + g * 4);
      float4 v0 = unpack_bf16_4(hwb[(size_t)c.x * 16 + q]);
      float4 v1 = unpack_bf16_4(hwb[(size_t)c.y * 16 + q]);
      float4 v2 = unpack_bf16_4(hwb[(size_t)c.z * 16 + q]);
      float4 v3 = unpack_bf16_4(hwb[(size_t)c.w * 16 + q]);
      float ax = v0.x + v1.x, bx = v2.x + v3.x;
      float ay = v0.y + v1.y, by = v2.y + v3.y;
      float az = v0.z + v1.z, bz = v2.z + v3.z;
      float aw = v0.w + v1.w, bw = v2.w + v3.w;
      acc.x += ax + bx;
      acc.y += ay + by;
      acc.z += az + bz;
      acc.w += aw + bw;
    }
    // combine the 4 quarter-wave partials (lanes q, q+16, q+32, q+48)
#pragma unroll
    for (int o = 16; o <= 32; o <<= 1) {
      acc.x += __shfl_xor(acc.x, o);
      acc.y += __shfl_xor(acc.y, o);
      acc.z += __shfl_xor(acc.z, o);
      acc.w += __shfl_xor(acc.w, o);
    }
    if (g == 0) {
      float dd = dinv[wid];
      float4 b = bias4[q];
      acc.x = fmaf(dd, acc.x, b.x);
      acc.y = fmaf(dd, acc.y, b.y);
      acc.z = fmaf(dd, acc.z, b.z);
      acc.w = fmaf(dd, acc.w, b.w);
      out4[(size_t)wid * 16 + q] = acc;
      s1 += acc.x + acc.y + acc.z + acc.w;
      s2 += acc.x * acc.x + acc.y * acc.y + acc.z * acc.z + acc.w * acc.w;
    }
  }
  // one full-wave reduce per wave (only g==0 lanes hold nonzero partials)
#pragma unroll
  for (int o = 1; o <= 32; o <<= 1) {
    s1 += __shfl_xor(s1, o);
    s2 += __shfl_xor(s2, o);
  }
  __shared__ float red1[4], red2[4];
  if (lane == 0) { red1[w] = s1; red2[w] = s2; }
  __syncthreads();
  if (t == 0) {
    double a = (double)red1[0] + (double)red1[1] + (double)red1[2] + (double)red1[3];
    double b = (double)red2[0] + (double)red2[1] + (double)red2[2] + (double)red2[3];
    double* bp = buckets + (size_t)(blockIdx.x & (NBUCK - 1)) * BSTRIDE;
    atomicAdd(&bp[0], a);
    atomicAdd(&bp[1], b);
  }
}

// final layer: in-place ln+relu on d_out (stats reduced in-block; grid-stride)
__global__ __launch_bounds__(256) void norm_relu_k(float4* __restrict__ io, const float* __restrict__ lnw,
                                                   const float* __restrict__ lnb,
                                                   const double* __restrict__ buckets, int M, int n4) {
  float mean, rstd;
  ln_stats(buckets, M, &mean, &rstd);
  for (int i = blockIdx.x * 256 + threadIdx.x; i < n4; i += gridDim.x * 256) {
    float4 v = io[i];
    int c = (i & 15) * 4;
    v.x = fmaxf(fmaf((v.x - mean) * rstd, lnw[c + 0], lnb[c + 0]), 0.f);
    v.y = fmaxf(fmaf((v.y - mean) * rstd, lnw[c + 1], lnb[c + 1]), 0.f);
    v.z = fmaxf(fmaf((v.z - mean) * rstd, lnw[c + 2], lnb[c + 2]), 0.f);
    v.w = fmaxf(fmaf((v.w - mean) * rstd, lnw[c + 3], lnb[c + 3]), 0.f);
    io[i] = v;
  }
}

// ---------------- launch ----------------

extern "C" void kernel_launch(void* const* d_in, const int* in_sizes, int n_in,
                              void* d_out, int out_size, void* d_ws, size_t ws_size,
                              hipStream_t stream) {
  const float* x = (const float*)d_in[0];
  const int* ei = (const int*)d_in[1];
  const float* Ws = (const float*)d_in[2];
  const float* bs = (const float*)d_in[3];
  const float* lnw = (const float*)d_in[4];
  const float* lnb = (const float*)d_in[5];
  float* out = (float*)d_out;

  const int N = in_sizes[0] / DD;
  const int E = in_sizes[1] / 2;
  const int L = in_sizes[2] / (DD * DD);
  const int* srcp = ei;
  const int* dstp = ei + E;
  const int nbkt = (N + 511) >> 9;  // <= 256 for N <= 131072

  char* p = (char*)d_ws;
  size_t ofs = 0;
  auto carve = [&](size_t bytes) -> void* {
    void* r = p + ofs;
    ofs = (ofs + bytes + 255) & ~(size_t)255;
    return r;
  };
  int* gcur = (int*)carve((size_t)256 * GSTRIDE * 4);
  int* bbase = (int*)carve((size_t)256 * 4);
  unsigned* slots = (unsigned*)carve((size_t)256 * CAP * 4);
  double* buckets = (double*)carve((size_t)NBUCK * BSTRIDE * 8 * 4);  // per-layer sets
  int2* off2 = (int2*)carve((size_t)N * 8);
  float* dinv = (float*)carve((size_t)N * 4);
  int* csr = (int*)carve(((size_t)E + (size_t)nbkt * BSLACK + 64) * 4);
  uint4* hwb = (uint4*)carve((size_t)(N + 1) * DD * 2);  // bf16 dinv*(h@W), +1 zero row

  hipMemsetAsync(gcur, 0, (size_t)256 * GSTRIDE * 4, stream);
  hipMemsetAsync(buckets, 0, (size_t)NBUCK * BSTRIDE * 8 * 4, stream);
  hipMemsetAsync(hwb + (size_t)N * 8, 0, DD * 2, stream);  // sentinel row N = 0

  int nTiles = (E + TILE - 1) / TILE;
  bucket_a_k<<<nTiles, 256, 0, stream>>>(srcp, dstp, gcur, slots, E);
  scan_nb_k<<<1, 256, 0, stream>>>(gcur, bbase, nbkt);
  bucket_b_k<<<nbkt, 256, 0, stream>>>(slots, gcur, bbase, off2, dinv, csr, N);

  int gGemm = (N + 63) / 64;
  int gAgg = (N + 31) / 32;  // 4 waves/block, 8 nodes/wave
  for (int l = 0; l < L; ++l) {
    const float* in = (l == 0) ? x : out;
    const float* plnw = (l == 0) ? lnw : lnw + (l - 1) * DD;
    const float* plnb = (l == 0) ? lnb : lnb + (l - 1) * DD;
    const double* pbuck = buckets + (size_t)((l == 0) ? 0 : (l - 1)) * NBUCK * BSTRIDE;
    gemm_mfma_k<<<gGemm, 256, 0, stream>>>(in, Ws + (size_t)l * DD * DD, hwb, dinv, plnw, plnb,
                                           pbuck, N * DD, (l > 0) ? 1 : 0, N);
    double* lbuck = buckets + (size_t)l * NBUCK * BSTRIDE;
    agg_k<<<gAgg, 256, 0, stream>>>((const uint2*)hwb, off2, csr, dinv,
                                    (const float4*)(bs + (size_t)l * DD), (float4*)out,
                                    lbuck, N);
  }
  norm_relu_k<<<1024, 256, 0, stream>>>((float4*)out, lnw + (size_t)(L - 1) * DD,
                                        lnb + (size_t)(L - 1) * DD,
                                        buckets + (size_t)(L - 1) * NBUCK * BSTRIDE,
                                        N * DD, N * (DD / 4));
}

// Round 11
// 307.207 us; speedup vs baseline: 1.2594x; 1.0149x over previous
//
#include <hip/hip_runtime.h>

#define DD 64
#define NBUCK 256
#define BSTRIDE 32   // doubles; 256B spacing -> distinct L2 lines
#define CAP 13312    // slots per coarse bucket (max observed ~8600, 1.5x margin)
#define GSTRIDE 16   // ints; 64B spacing for global cursors
#define TILE 4096    // edges per bucket_a block
#define BSLACK 8192  // per-bucket csr padding slack (512 nodes * 15 max pad)

typedef __attribute__((ext_vector_type(8))) short bf16x8;
typedef __attribute__((ext_vector_type(4))) float f32x4;

__device__ __forceinline__ unsigned short f2bf(float f) {
  unsigned u = __float_as_uint(f);
  return (unsigned short)((u + 0x7FFFu + ((u >> 16) & 1u)) >> 16);
}

__device__ __forceinline__ float4 unpack_bf16_4(uint2 p) {
  float4 f;
  f.x = __uint_as_float(p.x << 16);
  f.y = __uint_as_float(p.x & 0xFFFF0000u);
  f.z = __uint_as_float(p.y << 16);
  f.w = __uint_as_float(p.y & 0xFFFF0000u);
  return f;
}

// block-wide LN stats from the 256 reduction buckets (blockDim must be 256)
__device__ __forceinline__ void ln_stats(const double* __restrict__ buckets, int M,
                                         float* mean_out, float* rstd_out) {
  __shared__ double ra[4], rb[4];
  __shared__ float sm[2];
  int t = threadIdx.x;
  double a = buckets[(size_t)t * BSTRIDE];
  double b = buckets[(size_t)t * BSTRIDE + 1];
#pragma unroll
  for (int o = 1; o <= 32; o <<= 1) {
    a += __shfl_xor(a, o);
    b += __shfl_xor(b, o);
  }
  if ((t & 63) == 0) { ra[t >> 6] = a; rb[t >> 6] = b; }
  __syncthreads();
  if (t == 0) {
    double s1 = ra[0] + ra[1] + ra[2] + ra[3];
    double s2 = rb[0] + rb[1] + rb[2] + rb[3];
    double mean = s1 / M;
    double var = s2 / M - mean * mean;
    sm[0] = (float)mean;
    sm[1] = (float)rsqrt(var + 1e-5);
  }
  __syncthreads();
  *mean_out = sm[0];
  *rstd_out = sm[1];
}

// ---------------- CSR build: two-pass bucket sort ----------------

// Pass A: group edges by coarse bucket (dst>>9). Packed entry = src | (dst&511)<<17.
// gcur holds COUNTS (memset 0); slot base = t*CAP + old_count.
__global__ __launch_bounds__(256) void bucket_a_k(const int* __restrict__ src, const int* __restrict__ dst,
                                                  int* __restrict__ gcur, unsigned* __restrict__ slots, int E) {
  __shared__ int hist[256], cur[256], hbase[256];
  int t = threadIdx.x;
  hist[t] = 0;
  cur[t] = 0;
  __syncthreads();
  int t0 = blockIdx.x * TILE;
  unsigned pk[16];
  int bk[16];
#pragma unroll
  for (int k = 0; k < 16; ++k) {
    int e = t0 + k * 256 + t;
    if (e < E) {
      int s = src[e], d = dst[e];
      bk[k] = d >> 9;
      pk[k] = (unsigned)s | ((unsigned)(d & 511) << 17);
      atomicAdd(&hist[bk[k]], 1);
    } else {
      bk[k] = -1;
      pk[k] = 0;
    }
  }
  __syncthreads();
  if (hist[t] > 0) hbase[t] = t * CAP + atomicAdd(&gcur[t * GSTRIDE], hist[t]);
  __syncthreads();
#pragma unroll
  for (int k = 0; k < 16; ++k) {
    if (bk[k] >= 0) {
      int r = atomicAdd(&cur[bk[k]], 1);
      slots[(size_t)hbase[bk[k]] + r] = pk[k];
    }
  }
}

// Pass B: per-bucket counting sort by local dst; writes off2 (start, padded_end),
// dinv, csr (src-only 4B). Segment padded to x16 with sentinel N (hwb row N = 0).
// Bucket-base scan (over the 256 raw counts) is done in-block: no scan kernel.
__global__ __launch_bounds__(256) void bucket_b_k(const unsigned* __restrict__ slots,
                                                  const int* __restrict__ gcur,
                                                  int2* __restrict__ off2, float* __restrict__ dinv,
                                                  int* __restrict__ csr, int N, int nbkt) {
  __shared__ int hist[512], excl[512], ts[256];
  __shared__ int sh_cbase;
  int b = blockIdx.x, t = threadIdx.x;
  int base = b * CAP;
  int cnt = gcur[b * GSTRIDE];
  if (cnt > CAP) cnt = CAP;
  int node0 = b << 9;
  // in-block exclusive scan of all bucket counts -> this bucket's csr base
  int c = (t < nbkt) ? gcur[t * GSTRIDE] : 0;
  ts[t] = c;
  __syncthreads();
  for (int o = 1; o < 256; o <<= 1) {
    int u = (t >= o) ? ts[t - o] : 0;
    __syncthreads();
    ts[t] += u;
    __syncthreads();
  }
  if (t == b) sh_cbase = ts[t] - c + b * BSLACK;
  hist[t] = 0;
  hist[t + 256] = 0;
  __syncthreads();
  int cbase = sh_cbase;
  for (int i = t; i < cnt; i += 256) atomicAdd(&hist[slots[(size_t)base + i] >> 17], 1);
  __syncthreads();
  int h0 = hist[2 * t], h1 = hist[2 * t + 1];
  int p0 = (h0 + 15) & ~15, p1 = (h1 + 15) & ~15;
  int pair = p0 + p1;
  ts[t] = pair;
  __syncthreads();
  for (int o = 1; o < 256; o <<= 1) {
    int u = (t >= o) ? ts[t - o] : 0;
    __syncthreads();
    ts[t] += u;
    __syncthreads();
  }
  int ep = ts[t] - pair;
  int start0 = cbase + ep, start1 = cbase + ep + p0;
  int j0 = node0 + 2 * t, j1 = j0 + 1;
  if (j0 < N) { off2[j0] = make_int2(start0, start0 + p0); dinv[j0] = rsqrtf((float)h0 + 1.0f); }
  if (j1 < N) { off2[j1] = make_int2(start1, start1 + p1); dinv[j1] = rsqrtf((float)h1 + 1.0f); }
  excl[2 * t] = start0;
  excl[2 * t + 1] = start1;
  __syncthreads();
  for (int i = t; i < cnt; i += 256) {
    unsigned e = slots[(size_t)base + i];
    int pos = atomicAdd(&excl[e >> 17], 1);
    csr[pos] = (int)(e & 0x1FFFFu);
  }
  __syncthreads();
  // sentinel-fill the padding of this thread's two nodes
  for (int i = h0; i < p0; ++i) csr[start0 + i] = N;
  for (int i = h1; i < p1; ++i) csr[start1 + i] = N;
}

// ---------------- per-layer kernels ----------------

// MFMA gemm: hwb[row] = bf16( dinv[row] * (act(in[row]) @ W) )
// act = id (l=0) or relu(ln(.)); LN stats reduced in-block (finalize fused).
// 4 waves/block, 64 rows/block; wave w does rows [w*16, w*16+16) x all 64 cols
// via 2 k-steps x 4 col-tiles of v_mfma_f32_16x16x32_bf16.
__global__ __launch_bounds__(256) void gemm_mfma_k(const float* __restrict__ in, const float* __restrict__ W,
                                                   uint4* __restrict__ hwb, const float* __restrict__ dinv,
                                                   const float* __restrict__ lnw, const float* __restrict__ lnb,
                                                   const double* __restrict__ buckets, int M,
                                                   int applyLn, int n) {
  __shared__ unsigned short ctile[4][16][72];  // 72: pad breaks 4-row bank alias, keeps 16B align
  int t = threadIdx.x;
  int w = t >> 6, lane = t & 63;
  int lm = lane & 15, lk = lane >> 4;  // fragment row/col = lm, k-group = lk
  float mean = 0.f, rstd = 1.f;
  if (applyLn) ln_stats(buckets, M, &mean, &rstd);

  // B fragments: bfrag[ks][ct][j] = W[ks*32 + lk*8 + j][ct*16 + lm]
  bf16x8 bfrag[2][4];
#pragma unroll
  for (int ks = 0; ks < 2; ++ks)
#pragma unroll
    for (int ct = 0; ct < 4; ++ct) {
      bf16x8 bb;
      int col = ct * 16 + lm;
      int kb = ks * 32 + lk * 8;
#pragma unroll
      for (int j = 0; j < 8; ++j) bb[j] = (short)f2bf(W[(kb + j) * 64 + col]);
      bfrag[ks][ct] = bb;
    }

  int row = blockIdx.x * 64 + w * 16 + lm;
  bool valid = row < n;
  // A fragments: afrag[ks][j] = act(in[row][ks*32 + lk*8 + j])
  bf16x8 afrag[2];
#pragma unroll
  for (int ks = 0; ks < 2; ++ks) {
    float4 v0 = make_float4(0.f, 0.f, 0.f, 0.f), v1 = v0;
    if (valid) {
      const float4* ip = (const float4*)in + (size_t)row * 16 + ks * 8 + lk * 2;
      v0 = ip[0];
      v1 = ip[1];
    }
    float vals[8] = {v0.x, v0.y, v0.z, v0.w, v1.x, v1.y, v1.z, v1.w};
    if (applyLn) {
      int cb = ks * 32 + lk * 8;
#pragma unroll
      for (int j = 0; j < 8; ++j)
        vals[j] = fmaxf(fmaf((vals[j] - mean) * rstd, lnw[cb + j], lnb[cb + j]), 0.f);
    }
    bf16x8 aa;
#pragma unroll
    for (int j = 0; j < 8; ++j) aa[j] = (short)f2bf(vals[j]);
    afrag[ks] = aa;
  }

  f32x4 acc[4];
#pragma unroll
  for (int ct = 0; ct < 4; ++ct) acc[ct] = (f32x4){0.f, 0.f, 0.f, 0.f};
#pragma unroll
  for (int ks = 0; ks < 2; ++ks)
#pragma unroll
    for (int ct = 0; ct < 4; ++ct)
      acc[ct] = __builtin_amdgcn_mfma_f32_16x16x32_bf16(afrag[ks], bfrag[ks][ct], acc[ct], 0, 0, 0);

  // epilogue: C[crow][ccol]: ccol = ct*16+lm, crow = lk*4 + r ; scale by dinv, pack bf16
#pragma unroll
  for (int r = 0; r < 4; ++r) {
    int grow = blockIdx.x * 64 + w * 16 + lk * 4 + r;
    float di = (grow < n) ? dinv[grow] : 0.f;
#pragma unroll
    for (int ct = 0; ct < 4; ++ct)
      ctile[w][lk * 4 + r][ct * 16 + lm] = f2bf(acc[ct][r] * di);
  }
  __syncthreads();
  // coalesced store: lane handles row lane>>2, quarter lane&3 (16 bf16 = 2 uint4)
  int srow = lane >> 2, sq = lane & 3;
  int grow = blockIdx.x * 64 + w * 16 + srow;
  if (grow < n) {
    const uint4* lp = (const uint4*)&ctile[w][srow][sq * 16];
    hwb[(size_t)grow * 8 + sq * 2 + 0] = lp[0];
    hwb[(size_t)grow * 8 + sq * 2 + 1] = lp[1];
  }
}

// 8 nodes per wave-task; quarter-wave (16 lanes) per edge, 4 bf16 (uint2) per lane.
// Grid-stride over tasks at exactly 8 blocks/CU so all waves are co-resident.
// Sentinel-padded CSR: no predicates in the edge loop; int4 broadcast csr loads.
// LN s1/s2 kept in registers across all tasks; one reduce+atomic per block.
__global__ __launch_bounds__(256) void agg_k(const uint2* __restrict__ hwb, const int2* __restrict__ off2,
                                             const int* __restrict__ csr, const float* __restrict__ dinv,
                                             const float4* __restrict__ bias4, float4* __restrict__ out4,
                                             double* __restrict__ buckets, int n, int ntask) {
  int t = threadIdx.x;
  int lane = t & 63;
  int w = t >> 6;
  int g = lane >> 4, q = lane & 15;
  float s1 = 0.f, s2 = 0.f;
  for (int task = blockIdx.x * 4 + w; task < ntask; task += gridDim.x * 4) {
    int wbase = task * 8;
#pragma unroll 1
    for (int ni = 0; ni < 8; ++ni) {
      int wid = wbase + ni;
      if (wid >= n) break;
      int2 oo = off2[wid];
      float4 acc = make_float4(0.f, 0.f, 0.f, 0.f);
      if (g == 0) acc = unpack_bf16_4(hwb[(size_t)wid * 16 + q]);  // self term
      for (int base = oo.x; base < oo.y; base += 16) {
        int4 c = *(const int4*)(csr + base + g * 4);
        float4 v0 = unpack_bf16_4(hwb[(size_t)c.x * 16 + q]);
        float4 v1 = unpack_bf16_4(hwb[(size_t)c.y * 16 + q]);
        float4 v2 = unpack_bf16_4(hwb[(size_t)c.z * 16 + q]);
        float4 v3 = unpack_bf16_4(hwb[(size_t)c.w * 16 + q]);
        float ax = v0.x + v1.x, bx = v2.x + v3.x;
        float ay = v0.y + v1.y, by = v2.y + v3.y;
        float az = v0.z + v1.z, bz = v2.z + v3.z;
        float aw = v0.w + v1.w, bw = v2.w + v3.w;
        acc.x += ax + bx;
        acc.y += ay + by;
        acc.z += az + bz;
        acc.w += aw + bw;
      }
      // combine the 4 quarter-wave partials (lanes q, q+16, q+32, q+48)
#pragma unroll
      for (int o = 16; o <= 32; o <<= 1) {
        acc.x += __shfl_xor(acc.x, o);
        acc.y += __shfl_xor(acc.y, o);
        acc.z += __shfl_xor(acc.z, o);
        acc.w += __shfl_xor(acc.w, o);
      }
      if (g == 0) {
        float dd = dinv[wid];
        float4 b = bias4[q];
        acc.x = fmaf(dd, acc.x, b.x);
        acc.y = fmaf(dd, acc.y, b.y);
        acc.z = fmaf(dd, acc.z, b.z);
        acc.w = fmaf(dd, acc.w, b.w);
        out4[(size_t)wid * 16 + q] = acc;
        s1 += acc.x + acc.y + acc.z + acc.w;
        s2 += acc.x * acc.x + acc.y * acc.y + acc.z * acc.z + acc.w * acc.w;
      }
    }
  }
  // one full-wave reduce per wave (only g==0 lanes hold nonzero partials)
#pragma unroll
  for (int o = 1; o <= 32; o <<= 1) {
    s1 += __shfl_xor(s1, o);
    s2 += __shfl_xor(s2, o);
  }
  __shared__ float red1[4], red2[4];
  if (lane == 0) { red1[w] = s1; red2[w] = s2; }
  __syncthreads();
  if (t == 0) {
    double a = (double)red1[0] + (double)red1[1] + (double)red1[2] + (double)red1[3];
    double b = (double)red2[0] + (double)red2[1] + (double)red2[2] + (double)red2[3];
    double* bp = buckets + (size_t)(blockIdx.x & (NBUCK - 1)) * BSTRIDE;
    atomicAdd(&bp[0], a);
    atomicAdd(&bp[1], b);
  }
}

// final layer: in-place ln+relu on d_out (stats reduced in-block; grid-stride)
__global__ __launch_bounds__(256) void norm_relu_k(float4* __restrict__ io, const float* __restrict__ lnw,
                                                   const float* __restrict__ lnb,
                                                   const double* __restrict__ buckets, int M, int n4) {
  float mean, rstd;
  ln_stats(buckets, M, &mean, &rstd);
  for (int i = blockIdx.x * 256 + threadIdx.x; i < n4; i += gridDim.x * 256) {
    float4 v = io[i];
    int c = (i & 15) * 4;
    v.x = fmaxf(fmaf((v.x - mean) * rstd, lnw[c + 0], lnb[c + 0]), 0.f);
    v.y = fmaxf(fmaf((v.y - mean) * rstd, lnw[c + 1], lnb[c + 1]), 0.f);
    v.z = fmaxf(fmaf((v.z - mean) * rstd, lnw[c + 2], lnb[c + 2]), 0.f);
    v.w = fmaxf(fmaf((v.w - mean) * rstd, lnw[c + 3], lnb[c + 3]), 0.f);
    io[i] = v;
  }
}

// ---------------- launch ----------------

extern "C" void kernel_launch(void* const* d_in, const int* in_sizes, int n_in,
                              void* d_out, int out_size, void* d_ws, size_t ws_size,
                              hipStream_t stream) {
  const float* x = (const float*)d_in[0];
  const int* ei = (const int*)d_in[1];
  const float* Ws = (const float*)d_in[2];
  const float* bs = (const float*)d_in[3];
  const float* lnw = (const float*)d_in[4];
  const float* lnb = (const float*)d_in[5];
  float* out = (float*)d_out;

  const int N = in_sizes[0] / DD;
  const int E = in_sizes[1] / 2;
  const int L = in_sizes[2] / (DD * DD);
  const int* srcp = ei;
  const int* dstp = ei + E;
  const int nbkt = (N + 511) >> 9;  // <= 256 for N <= 131072

  char* p = (char*)d_ws;
  size_t ofs = 0;
  auto carve = [&](size_t bytes) -> void* {
    void* r = p + ofs;
    ofs = (ofs + bytes + 255) & ~(size_t)255;
    return r;
  };
  int* gcur = (int*)carve((size_t)256 * GSTRIDE * 4);
  unsigned* slots = (unsigned*)carve((size_t)256 * CAP * 4);
  double* buckets = (double*)carve((size_t)NBUCK * BSTRIDE * 8 * 4);  // per-layer sets
  int2* off2 = (int2*)carve((size_t)N * 8);
  float* dinv = (float*)carve((size_t)N * 4);
  int* csr = (int*)carve(((size_t)E + (size_t)nbkt * BSLACK + 64) * 4);
  uint4* hwb = (uint4*)carve((size_t)(N + 1) * DD * 2);  // bf16 dinv*(h@W), +1 zero row

  hipMemsetAsync(gcur, 0, (size_t)256 * GSTRIDE * 4, stream);
  hipMemsetAsync(buckets, 0, (size_t)NBUCK * BSTRIDE * 8 * 4, stream);
  hipMemsetAsync(hwb + (size_t)N * 8, 0, DD * 2, stream);  // sentinel row N = 0

  int nTiles = (E + TILE - 1) / TILE;
  bucket_a_k<<<nTiles, 256, 0, stream>>>(srcp, dstp, gcur, slots, E);
  bucket_b_k<<<nbkt, 256, 0, stream>>>(slots, gcur, off2, dinv, csr, N, nbkt);

  int gGemm = (N + 63) / 64;
  int ntask = (N + 7) / 8;
  for (int l = 0; l < L; ++l) {
    const float* in = (l == 0) ? x : out;
    const float* plnw = (l == 0) ? lnw : lnw + (l - 1) * DD;
    const float* plnb = (l == 0) ? lnb : lnb + (l - 1) * DD;
    const double* pbuck = buckets + (size_t)((l == 0) ? 0 : (l - 1)) * NBUCK * BSTRIDE;
    gemm_mfma_k<<<gGemm, 256, 0, stream>>>(in, Ws + (size_t)l * DD * DD, hwb, dinv, plnw, plnb,
                                           pbuck, N * DD, (l > 0) ? 1 : 0, N);
    double* lbuck = buckets + (size_t)l * NBUCK * BSTRIDE;
    agg_k<<<2048, 256, 0, stream>>>((const uint2*)hwb, off2, csr, dinv,
                                    (const float4*)(bs + (size_t)l * DD), (float4*)out,
                                    lbuck, N, ntask);
  }
  norm_relu_k<<<1024, 256, 0, stream>>>((float4*)out, lnw + (size_t)(L - 1) * DD,
                                        lnb + (size_t)(L - 1) * DD,
                                        buckets + (size_t)(L - 1) * NBUCK * BSTRIDE,
                                        N * DD, N * (DD / 4));
}